// Round 1
// baseline (244.301 us; speedup 1.0000x reference)
//
#include <hip/hip_runtime.h>
#include <stdint.h>

#define NB 256
#define NL 128
#define ND1 512
#define ND2 512

#define BN 128              // j-tile width per block
#define BK 64               // k-tile depth
#define NKT (ND1 / BK)      // 8 k-tiles
#define LDST 72             // LDS row stride (bf16 elems): 144 B rows -> 16B-aligned, bank phase +4/row

typedef float float4_t __attribute__((ext_vector_type(4)));
typedef __bf16 bf16x8_t __attribute__((ext_vector_type(8)));
typedef unsigned short ushort4_t __attribute__((ext_vector_type(4)));
typedef unsigned short ushort8_t __attribute__((ext_vector_type(8)));

// fp32 -> bf16 round-to-nearest-even (bit trick; inputs are normal randoms)
__device__ __forceinline__ unsigned short f2bf(float f) {
    unsigned int u = __float_as_uint(f);
    u += 0x7FFFu + ((u >> 16) & 1u);
    return (unsigned short)(u >> 16);
}

__global__ __launch_bounds__(256, 3) void pdot_kernel(
    const float* __restrict__ t1, const float* __restrict__ t2,
    const int* __restrict__ pidx, const float* __restrict__ wgt,
    float* __restrict__ out)
{
    __shared__ unsigned short sA[NL * LDST];   // T1 tile, bf16: [128 rows m][64 k + pad]
    __shared__ unsigned short sB[BN * LDST];   // W tile transposed, bf16: [128 rows n][64 k + pad]

    const int g  = blockIdx.x;
    const int b  = g & (NB - 1);   // batch in low bits -> all 4 j-tiles of b share g%8 (XCD) for T1 L2 reuse
    const int jt = g >> 8;
    const int j0 = jt * BN;

    const int t  = threadIdx.x;
    const int wv = t >> 6;         // wave 0..3 -> rows wv*32..wv*32+31
    const int ln = t & 63;
    const int nh = ln & 15;        // lane&15: MFMA col / m-index
    const int qd = ln >> 4;        // quad: MFMA k-group / row-group

    const int e = pidx[b];
    const float* t1p = t1  + (size_t)b * (NL * ND1);
    const float* t2p = t2  + (size_t)b * (NL * ND2) + j0;
    const float* wp  = wgt + (size_t)e * (ND1 * ND2) + j0;

    float4_t acc[2][8];
    #pragma unroll
    for (int i = 0; i < 2; ++i)
        #pragma unroll
        for (int j = 0; j < 8; ++j) {
            float4_t z = {0.f, 0.f, 0.f, 0.f};
            acc[i][j] = z;
        }

    // A staging map: per pass 16 rows x 64 k; lane = 4 consecutive k of one row (float4, 256B/16-lane coalesced)
    const int a_m = t >> 4;            // + p*16
    const int a_k = (t & 15) * 4;
    // W staging map: lane owns 8 strided k for one n; each dword load instr = 64B segments, write = ds_write_b128
    const int w_n  = ((t >> 4) & 7) * 16 + (t & 15);   // 0..127
    const int w_k8 = (t >> 7) * 8;                     // 0 or 8

    for (int kt = 0; kt < NKT; ++kt) {
        const int k0 = kt * BK;

        // ---- stage T1 tile -> sA (bf16), 8 passes
        #pragma unroll
        for (int p = 0; p < 8; ++p) {
            const int m = p * 16 + a_m;
            float4_t v = *(const float4_t*)(t1p + (size_t)m * ND1 + (k0 + a_k));
            ushort4_t u;
            u.x = f2bf(v.x); u.y = f2bf(v.y); u.z = f2bf(v.z); u.w = f2bf(v.w);
            *(ushort4_t*)(&sA[m * LDST + a_k]) = u;
        }

        // ---- stage W tile transposed -> sB[n][k] (bf16), 4 passes
        #pragma unroll
        for (int p = 0; p < 4; ++p) {
            const int kk = p * 16 + w_k8;
            const float* src = wp + (size_t)(k0 + kk) * ND2 + w_n;
            ushort8_t u;
            #pragma unroll
            for (int i = 0; i < 8; ++i)
                u[i] = f2bf(src[(size_t)i * ND2]);
            *(ushort8_t*)(&sB[w_n * LDST + kk]) = u;   // one ds_write_b128
        }

        __syncthreads();

        // ---- MFMA: 2 k-steps of 32; wave does 2 m-subtiles x 8 n-subtiles
        #pragma unroll
        for (int ks = 0; ks < 2; ++ks) {
            const int kf = ks * 32 + qd * 8;
            bf16x8_t af[2];
            bf16x8_t bfr[8];
            #pragma unroll
            for (int ms = 0; ms < 2; ++ms) {
                const int row = wv * 32 + ms * 16 + nh;
                af[ms] = __builtin_bit_cast(bf16x8_t, *(ushort8_t*)(&sA[row * LDST + kf]));
            }
            #pragma unroll
            for (int ns = 0; ns < 8; ++ns) {
                const int nr = ns * 16 + nh;
                bfr[ns] = __builtin_bit_cast(bf16x8_t, *(ushort8_t*)(&sB[nr * LDST + kf]));
            }
            #pragma unroll
            for (int ms = 0; ms < 2; ++ms)
                #pragma unroll
                for (int ns = 0; ns < 8; ++ns)
                    acc[ms][ns] = __builtin_amdgcn_mfma_f32_16x16x32_bf16(af[ms], bfr[ns], acc[ms][ns], 0, 0, 0);
        }

        __syncthreads();
    }

    // ---- epilogue: out[b,row] += sum_j Y[row,j]*t2[row,j] over this j-tile
    // C/D layout: col = ns*16 + nh, row = qd*4 + reg (verified m89/m91 mapping)
    #pragma unroll
    for (int ms = 0; ms < 2; ++ms) {
        #pragma unroll
        for (int r = 0; r < 4; ++r) {
            const int row = wv * 32 + ms * 16 + qd * 4 + r;
            float ps = 0.f;
            #pragma unroll
            for (int ns = 0; ns < 8; ++ns) {
                const float tv = t2p[(size_t)row * ND2 + ns * 16 + nh];
                ps += acc[ms][ns][r] * tv;
            }
            // reduce across the 16 lanes of this quad (same row, cols nh + 16*ns)
            ps += __shfl_xor(ps, 1);
            ps += __shfl_xor(ps, 2);
            ps += __shfl_xor(ps, 4);
            ps += __shfl_xor(ps, 8);
            if (nh == 0) atomicAdd(&out[b * NL + row], ps);
        }
    }
}

extern "C" void kernel_launch(void* const* d_in, const int* in_sizes, int n_in,
                              void* d_out, int out_size, void* d_ws, size_t ws_size,
                              hipStream_t stream)
{
    const float* t1  = (const float*)d_in[0];
    const float* t2  = (const float*)d_in[1];
    const int* pidx  = (const int*)d_in[2];
    const float* wgt = (const float*)d_in[3];
    float* out = (float*)d_out;

    // d_out is poisoned 0xAA before every launch; atomics need zeros
    hipMemsetAsync(out, 0, (size_t)out_size * sizeof(float), stream);
    pdot_kernel<<<dim3(NB * (ND2 / BN)), dim3(256), 0, stream>>>(t1, t2, pidx, wgt, out);
}

// Round 2
// 242.590 us; speedup vs baseline: 1.0071x; 1.0071x over previous
//
#include <hip/hip_runtime.h>
#include <stdint.h>

#define NB 256
#define NL 128
#define ND1 512
#define ND2 512

#define BI 128              // i-tile width per block (n-dim of GEMM)
#define BK 64               // k-tile depth (j-dim)
#define NKT (ND2 / BK)      // 8 k-tiles
#define LDST 72             // LDS row stride (bf16 elems): 144 B rows, 16B-aligned, bank phase +4/row

typedef float float4_t __attribute__((ext_vector_type(4)));
typedef __bf16 bf16x8_t __attribute__((ext_vector_type(8)));
typedef unsigned short ushort4_t __attribute__((ext_vector_type(4)));
typedef unsigned short ushort8_t __attribute__((ext_vector_type(8)));

// fp32 -> bf16 round-to-nearest-even
__device__ __forceinline__ unsigned short f2bf(float f) {
    unsigned int u = __float_as_uint(f);
    u += 0x7FFFu + ((u >> 16) & 1u);
    return (unsigned short)(u >> 16);
}

// Z = T2 (128 x 512, k=j) x W^T (512 x 512; B[n=i][k=j], rows k-contiguous!)
// out[b,l] = sum_i Z[l,i] * t1[b,l,i]
__global__ __launch_bounds__(256, 4) void pdot_kernel(
    const float* __restrict__ t1, const float* __restrict__ t2,
    const int* __restrict__ pidx, const float* __restrict__ wgt,
    float* __restrict__ out)
{
    __shared__ unsigned short sA[NL * LDST];   // T2 tile bf16: [128 l][64 j + pad]
    __shared__ unsigned short sB[BI * LDST];   // W  tile bf16: [128 i][64 j + pad]

    const int g  = blockIdx.x;
    const int b  = g & (NB - 1);   // batch in low bits: all 4 i-tiles of b share g%8 (XCD) -> t1/t2 L2 reuse
    const int it = g >> 8;
    const int i0 = it * BI;

    const int t  = threadIdx.x;
    const int wv = t >> 6;         // wave 0..3 -> l-rows wv*32..wv*32+31
    const int ln = t & 63;
    const int nh = ln & 15;
    const int qd = ln >> 4;

    const int e = pidx[b];
    const float* aPtr  = t2  + (size_t)b * (NL * ND2);            // A source (l-major, j contig)
    const float* bPtr  = wgt + (size_t)e * (ND1 * ND2) + (size_t)i0 * ND2;  // B source (i-major, j contig)
    const float* t1p   = t1  + (size_t)b * (NL * ND1) + i0;       // epilogue dot operand

    float4_t acc[2][8];
    #pragma unroll
    for (int i = 0; i < 2; ++i)
        #pragma unroll
        for (int j = 0; j < 8; ++j) {
            float4_t z = {0.f, 0.f, 0.f, 0.f};
            acc[i][j] = z;
        }

    // identical staging map for both tiles: pass p covers rows p*16..p*16+15,
    // lane (t&15) owns one 16B chunk -> fully coalesced float4, 8 passes/tile
    const int s_row = t >> 4;          // +p*16
    const int s_kq  = (t & 15) * 4;

    for (int kt = 0; kt < NKT; ++kt) {
        const int k0 = kt * BK;

        #pragma unroll
        for (int p = 0; p < 8; ++p) {
            const int row = p * 16 + s_row;
            float4_t va = *(const float4_t*)(aPtr + (size_t)row * ND2 + (k0 + s_kq));
            float4_t vb = *(const float4_t*)(bPtr + (size_t)row * ND2 + (k0 + s_kq));
            ushort4_t ua, ub;
            ua.x = f2bf(va.x); ua.y = f2bf(va.y); ua.z = f2bf(va.z); ua.w = f2bf(va.w);
            ub.x = f2bf(vb.x); ub.y = f2bf(vb.y); ub.z = f2bf(vb.z); ub.w = f2bf(vb.w);
            *(ushort4_t*)(&sA[row * LDST + s_kq]) = ua;
            *(ushort4_t*)(&sB[row * LDST + s_kq]) = ub;
        }

        __syncthreads();

        #pragma unroll
        for (int ks = 0; ks < 2; ++ks) {
            const int kf = ks * 32 + qd * 8;
            bf16x8_t af[2];
            bf16x8_t bfr[8];
            #pragma unroll
            for (int ms = 0; ms < 2; ++ms) {
                const int row = wv * 32 + ms * 16 + nh;
                af[ms] = __builtin_bit_cast(bf16x8_t, *(ushort8_t*)(&sA[row * LDST + kf]));
            }
            #pragma unroll
            for (int ns = 0; ns < 8; ++ns) {
                const int nr = ns * 16 + nh;
                bfr[ns] = __builtin_bit_cast(bf16x8_t, *(ushort8_t*)(&sB[nr * LDST + kf]));
            }
            #pragma unroll
            for (int ms = 0; ms < 2; ++ms)
                #pragma unroll
                for (int ns = 0; ns < 8; ++ns)
                    acc[ms][ns] = __builtin_amdgcn_mfma_f32_16x16x32_bf16(af[ms], bfr[ns], acc[ms][ns], 0, 0, 0);
        }

        __syncthreads();
    }

    // epilogue: out[b,l] += sum over this i-tile of Z[l,i]*t1[l,i]
    // C/D: col(n=i) = ns*16+nh, row(m=l) = qd*4+r (+ms*16+wv*32)
    #pragma unroll
    for (int ms = 0; ms < 2; ++ms) {
        #pragma unroll
        for (int r = 0; r < 4; ++r) {
            const int row = wv * 32 + ms * 16 + qd * 4 + r;
            float ps = 0.f;
            #pragma unroll
            for (int ns = 0; ns < 8; ++ns) {
                const float tv = t1p[(size_t)row * ND1 + ns * 16 + nh];
                ps += acc[ms][ns][r] * tv;
            }
            ps += __shfl_xor(ps, 1);
            ps += __shfl_xor(ps, 2);
            ps += __shfl_xor(ps, 4);
            ps += __shfl_xor(ps, 8);
            if (nh == 0) atomicAdd(&out[b * NL + row], ps);
        }
    }
}

extern "C" void kernel_launch(void* const* d_in, const int* in_sizes, int n_in,
                              void* d_out, int out_size, void* d_ws, size_t ws_size,
                              hipStream_t stream)
{
    const float* t1  = (const float*)d_in[0];
    const float* t2  = (const float*)d_in[1];
    const int* pidx  = (const int*)d_in[2];
    const float* wgt = (const float*)d_in[3];
    float* out = (float*)d_out;

    hipMemsetAsync(out, 0, (size_t)out_size * sizeof(float), stream);
    pdot_kernel<<<dim3(NB * (ND1 / BI)), dim3(256), 0, stream>>>(t1, t2, pidx, wgt, out);
}